// Round 1
// baseline (52.087 us; speedup 1.0000x reference)
//
#include <hip/hip_runtime.h>

#define NS 8192   // samples
#define NC 512    // centers
#define NF 128    // features

// ---------------------------------------------------------------- build P = L L^T
__global__ void build_P(const float* __restrict__ pe, float* __restrict__ P) {
    int i = blockIdx.x, j = threadIdx.x;
    int offi = i * (i + 1) / 2;
    int offj = j * (j + 1) / 2;
    int m = min(i, j);
    float s = 0.f;
    for (int k = 0; k <= m; ++k) s = fmaf(pe[offi + k], pe[offj + k], s);
    P[i * NF + j] = s;
}

// ---------------------------------------------------------------- CP = centers @ P, q_c
__global__ void cp_qc(const float* __restrict__ centers, const float* __restrict__ P,
                      float* __restrict__ CP, float* __restrict__ qc) {
    int c = blockIdx.x, j = threadIdx.x;   // 128 threads
    __shared__ float cen[NF];
    __shared__ float red[2];
    cen[j] = centers[c * NF + j];
    __syncthreads();
    float s = 0.f;
#pragma unroll 8
    for (int k = 0; k < NF; ++k) s = fmaf(cen[k], P[k * NF + j], s);
    CP[c * NF + j] = s;
    float contrib = s * cen[j];
#pragma unroll
    for (int off = 32; off > 0; off >>= 1) contrib += __shfl_down(contrib, off, 64);
    if ((j & 63) == 0) red[j >> 6] = contrib;
    __syncthreads();
    if (j == 0) qc[c] = red[0] + red[1];
}

// ---------------------------------------------------------------- LDS tile staging (64 rows x 128, XOR chunk swizzle)
__device__ __forceinline__ void stage_tile(const float* __restrict__ src, int row0, float* lds) {
    int k4 = threadIdx.x & 31;      // float4 chunk within row
    int nb = threadIdx.x >> 5;      // 0..7
#pragma unroll
    for (int i = 0; i < 8; ++i) {
        int n = nb * 8 + i;
        float4 g = *(const float4*)&src[(size_t)(row0 + n) * NF + k4 * 4];
        *(float4*)&lds[n * NF + ((k4 ^ ((n >> 2) & 15)) << 2)] = g;
    }
}

// ---------------------------------------------------------------- q_x partials via XP tile GEMM (B = P rows, symmetric)
__global__ __launch_bounds__(256) void qx_kernel(const float* __restrict__ X, const float* __restrict__ P,
                                                 float* __restrict__ qxp) {
    __shared__ __align__(16) float As[64 * NF];
    __shared__ __align__(16) float Bs[64 * NF];
    __shared__ float part[64 * 17];
    int n0 = blockIdx.x * 64;
    int j0 = blockIdx.y * 64;
    stage_tile(X, n0, As);
    stage_tile(P, j0, Bs);
    __syncthreads();
    int tn = threadIdx.x & 15, tc = threadIdx.x >> 4;
    float acc[4][4] = {};
#pragma unroll 4
    for (int kq = 0; kq < 32; ++kq) {
        float a_[4][4], b_[4][4];
#pragma unroll
        for (int r = 0; r < 4; ++r) {
            *(float4*)a_[r] = *(const float4*)&As[(4 * tn + r) * NF + ((kq ^ tn) << 2)];
            *(float4*)b_[r] = *(const float4*)&Bs[(4 * tc + r) * NF + ((kq ^ tc) << 2)];
        }
#pragma unroll
        for (int i = 0; i < 4; ++i)
#pragma unroll
            for (int j = 0; j < 4; ++j)
#pragma unroll
                for (int d = 0; d < 4; ++d)
                    acc[i][j] = fmaf(a_[i][d], b_[j][d], acc[i][j]);
    }
    // s_i = sum_j XP[n][j] * X[n][j] over this block's j-range
    int chunk = ((blockIdx.y * 16 + tc) ^ tn) << 2;
#pragma unroll
    for (int i = 0; i < 4; ++i) {
        int n = 4 * tn + i;
        float4 xv = *(const float4*)&As[n * NF + chunk];
        float s = acc[i][0] * xv.x + acc[i][1] * xv.y + acc[i][2] * xv.z + acc[i][3] * xv.w;
        part[n * 17 + tc] = s;
    }
    __syncthreads();
    if (threadIdx.x < 64) {
        float s = 0.f;
#pragma unroll
        for (int t = 0; t < 16; ++t) s += part[threadIdx.x * 17 + t];
        qxp[blockIdx.y * NS + n0 + threadIdx.x] = s;
    }
}

// ---------------------------------------------------------------- cross GEMM + exp + weighted c-reduce -> partials
__global__ __launch_bounds__(256) void cross_kernel(const float* __restrict__ X, const float* __restrict__ CP,
                                                    const float* __restrict__ qxp, const float* __restrict__ qc,
                                                    const float* __restrict__ w, float* __restrict__ partials) {
    __shared__ __align__(16) float As[64 * NF];
    __shared__ __align__(16) float Bs[64 * NF];
    __shared__ float part[64 * 17];
    int n0 = blockIdx.x * 64;
    int c0 = blockIdx.y * 64;
    stage_tile(X, n0, As);
    stage_tile(CP, c0, Bs);
    __syncthreads();
    int tn = threadIdx.x & 15, tc = threadIdx.x >> 4;
    float acc[4][4] = {};
#pragma unroll 4
    for (int kq = 0; kq < 32; ++kq) {
        float a_[4][4], b_[4][4];
#pragma unroll
        for (int r = 0; r < 4; ++r) {
            *(float4*)a_[r] = *(const float4*)&As[(4 * tn + r) * NF + ((kq ^ tn) << 2)];
            *(float4*)b_[r] = *(const float4*)&Bs[(4 * tc + r) * NF + ((kq ^ tc) << 2)];
        }
#pragma unroll
        for (int i = 0; i < 4; ++i)
#pragma unroll
            for (int j = 0; j < 4; ++j)
#pragma unroll
                for (int d = 0; d < 4; ++d)
                    acc[i][j] = fmaf(a_[i][d], b_[j][d], acc[i][j]);
    }
    float qxv[4], qcv[4], wv[4];
#pragma unroll
    for (int i = 0; i < 4; ++i) {
        int n = n0 + 4 * tn + i;
        qxv[i] = qxp[n] + qxp[NS + n];
    }
#pragma unroll
    for (int j = 0; j < 4; ++j) {
        int c = c0 + 4 * tc + j;
        qcv[j] = qc[c];
        wv[j] = w[c];
    }
    const float HALF_LOG2E = 0.72134752044448169f;  // 0.5*log2(e)
#pragma unroll
    for (int i = 0; i < 4; ++i) {
        float s = 0.f;
#pragma unroll
        for (int j = 0; j < 4; ++j) {
            // exp(-0.5*(qx - 2*cross + qc)) = exp2((2*cross - qx - qc)*0.5*log2(e))
            float e = (2.f * acc[i][j] - qxv[i] - qcv[j]) * HALF_LOG2E;
            s = fmaf(exp2f(e), wv[j], s);
        }
        part[(4 * tn + i) * 17 + tc] = s;
    }
    __syncthreads();
    if (threadIdx.x < 64) {
        float s = 0.f;
#pragma unroll
        for (int t = 0; t < 16; ++t) s += part[threadIdx.x * 17 + t];
        partials[blockIdx.y * NS + n0 + threadIdx.x] = s;
    }
}

// ---------------------------------------------------------------- final reduce over 8 c-tiles
__global__ void reduce_out(const float* __restrict__ partials, float* __restrict__ out) {
    int n = blockIdx.x * blockDim.x + threadIdx.x;
    float s = 0.f;
#pragma unroll
    for (int ct = 0; ct < 8; ++ct) s += partials[ct * NS + n];
    out[n] = s;
}

extern "C" void kernel_launch(void* const* d_in, const int* in_sizes, int n_in,
                              void* d_out, int out_size, void* d_ws, size_t ws_size,
                              hipStream_t stream) {
    const float* X       = (const float*)d_in[0];
    const float* pe      = (const float*)d_in[1];
    const float* centers = (const float*)d_in[2];
    const float* w       = (const float*)d_in[3];
    float* out = (float*)d_out;
    float* ws  = (float*)d_ws;

    float* P        = ws;            // 16384 floats
    float* CP       = ws + 16384;    // 65536
    float* qc       = ws + 81920;    // 512
    float* qxp      = ws + 82432;    // 16384 (2 j-tiles x 8192)
    float* partials = ws + 98816;    // 65536 (8 c-tiles x 8192)

    build_P<<<128, 128, 0, stream>>>(pe, P);
    cp_qc<<<512, 128, 0, stream>>>(centers, P, CP, qc);
    qx_kernel<<<dim3(128, 2), 256, 0, stream>>>(X, P, qxp);
    cross_kernel<<<dim3(128, 8), 256, 0, stream>>>(X, CP, qxp, qc, w, partials);
    reduce_out<<<32, 256, 0, stream>>>(partials, out);
}

// Round 2
// 38.051 us; speedup vs baseline: 1.3689x; 1.3689x over previous
//
#include <hip/hip_runtime.h>

#define NS 8192
#define NC 512
#define NF 128

typedef short short8 __attribute__((ext_vector_type(8)));   // 8 bf16 = 4 VGPRs (guide §3)
typedef float f32x4 __attribute__((ext_vector_type(4)));

static __device__ __forceinline__ unsigned short f2bf(float f) {
    unsigned u = __float_as_uint(f);
    unsigned r = (u + 0x7fffu + ((u >> 16) & 1u)) >> 16;   // RNE
    return (unsigned short)r;
}
static __device__ __forceinline__ float bf2f(unsigned short b) {
    return __uint_as_float(((unsigned)b) << 16);
}

// ------------------------------------------------ prep: P = L L^T (fp32 + bf16) || X -> bf16
__global__ __launch_bounds__(256) void prep_kernel(const float* __restrict__ pe,
                                                   const float* __restrict__ X,
                                                   float* __restrict__ P,
                                                   short* __restrict__ Pb,
                                                   short* __restrict__ Xb) {
    int b = blockIdx.x, t = threadIdx.x;
    if (b < 64) {
        int idx = b * 256 + t;
        int i = idx >> 7, j = idx & 127;
        int m = min(i, j);
        const float* pi = pe + i * (i + 1) / 2;
        const float* pj = pe + j * (j + 1) / 2;
        float s = 0.f;
        for (int k = 0; k <= m; ++k) s = fmaf(pi[k], pj[k], s);
        P[idx] = s;
        Pb[idx] = (short)f2bf(s);
    } else {
        int base = (b - 64) * 2048 + t * 8;
        float4 v0 = *(const float4*)(X + base);
        float4 v1 = *(const float4*)(X + base + 4);
        short8 o;
        o[0] = (short)f2bf(v0.x); o[1] = (short)f2bf(v0.y);
        o[2] = (short)f2bf(v0.z); o[3] = (short)f2bf(v0.w);
        o[4] = (short)f2bf(v1.x); o[5] = (short)f2bf(v1.y);
        o[6] = (short)f2bf(v1.z); o[7] = (short)f2bf(v1.w);
        *(short8*)(Xb + base) = o;
    }
}

// ------------------------------------------------ CP = centers @ P (bf16), q_c
__global__ __launch_bounds__(256) void cpqc_kernel(const float* __restrict__ centers,
                                                   const float* __restrict__ P,
                                                   short* __restrict__ CPb,
                                                   float* __restrict__ qc) {
    __shared__ float cen[8 * NF];
    __shared__ float qcw[4][4];
    int t = threadIdx.x;
    int c0 = blockIdx.x * 8;
    *(float4*)&cen[t * 4] = *(const float4*)&centers[c0 * NF + t * 4];
    __syncthreads();
    int j = t & 127, h = t >> 7;     // h in {0,1}; thread handles centers h, h+2, h+4, h+6
    float acc[4] = {0.f, 0.f, 0.f, 0.f};
#pragma unroll 8
    for (int k = 0; k < NF; ++k) {
        float pv = P[k * NF + j];
#pragma unroll
        for (int m = 0; m < 4; ++m) acc[m] = fmaf(cen[(h + 2 * m) * NF + k], pv, acc[m]);
    }
    int wv = t >> 6, lane = t & 63;
#pragma unroll
    for (int m = 0; m < 4; ++m) {
        CPb[(c0 + h + 2 * m) * NF + j] = (short)f2bf(acc[m]);
        float v = acc[m] * cen[(h + 2 * m) * NF + j];
#pragma unroll
        for (int off = 32; off > 0; off >>= 1) v += __shfl_xor(v, off);
        if (lane == 0) qcw[wv][m] = v;
    }
    __syncthreads();
    if (t < 8) {
        int h2 = t & 1, m = t >> 1;   // c_local = h + 2m = t
        qc[c0 + t] = qcw[2 * h2][m] + qcw[2 * h2 + 1][m];
    }
}

// ------------------------------------------------ mega: q_x (MFMA) + cross (MFMA) + exp epilogue
__global__ __launch_bounds__(512) void mega_kernel(const short* __restrict__ Xb,
                                                   const short* __restrict__ Pb,
                                                   const short* __restrict__ CPb,
                                                   const float* __restrict__ qc,
                                                   const float* __restrict__ w,
                                                   float* __restrict__ out) {
    __shared__ float qxlds[8][32];
    __shared__ float qxfin[32];
    __shared__ float outlds[8][32];
    int t = threadIdx.x;
    int wv = t >> 6, lane = t & 63;
    int g = lane >> 4, r = lane & 15;
    int n0 = blockIdx.x * 32;

    // A fragments: rows n0+16s+r, k-chunk kk*32 + 8g (contiguous-8 per lane)
    const short8* Xv = (const short8*)Xb;      // row stride = 16 short8
    short8 a[2][4];
#pragma unroll
    for (int s = 0; s < 2; ++s)
#pragma unroll
        for (int kk = 0; kk < 4; ++kk)
            a[s][kk] = Xv[(size_t)(n0 + 16 * s + r) * 16 + kk * 4 + g];

    // ---------- phase 1: qx = diag(X P X^T), this wave's j-chunk = [16*wv, 16*wv+16)
    f32x4 aq[2];
    aq[0] = (f32x4){0.f, 0.f, 0.f, 0.f};
    aq[1] = (f32x4){0.f, 0.f, 0.f, 0.f};
    const short8* Pv = (const short8*)Pb;
#pragma unroll
    for (int kk = 0; kk < 4; ++kk) {
        short8 bfrag = Pv[(size_t)(16 * wv + r) * 16 + kk * 4 + g];
        aq[0] = __builtin_amdgcn_mfma_f32_16x16x32_bf16(a[0][kk], bfrag, aq[0], 0, 0, 0);
        aq[1] = __builtin_amdgcn_mfma_f32_16x16x32_bf16(a[1][kk], bfrag, aq[1], 0, 0, 0);
    }
#pragma unroll
    for (int s = 0; s < 2; ++s)
#pragma unroll
        for (int reg = 0; reg < 4; ++reg) {
            int rr = 16 * s + 4 * g + reg;                 // acc row = 4g+reg, col j = 16*wv + r
            float xv = bf2f((unsigned short)Xb[(size_t)(n0 + rr) * NF + 16 * wv + r]);
            float v = aq[s][reg] * xv;
            v += __shfl_xor(v, 1); v += __shfl_xor(v, 2);
            v += __shfl_xor(v, 4); v += __shfl_xor(v, 8);
            if (r == 0) qxlds[wv][rr] = v;
        }
    __syncthreads();
    if (t < 32) {
        float s = 0.f;
#pragma unroll
        for (int i = 0; i < 8; ++i) s += qxlds[i][t];
        qxfin[t] = s;
    }
    __syncthreads();

    // ---------- phase 2: cross vs centers [64*wv, 64*wv+64)
    f32x4 acc[2][4];
#pragma unroll
    for (int s = 0; s < 2; ++s)
#pragma unroll
        for (int ct = 0; ct < 4; ++ct) acc[s][ct] = (f32x4){0.f, 0.f, 0.f, 0.f};
    const short8* Cv = (const short8*)CPb;
#pragma unroll
    for (int kk = 0; kk < 4; ++kk) {
#pragma unroll
        for (int ct = 0; ct < 4; ++ct) {
            short8 bfrag = Cv[(size_t)(64 * wv + 16 * ct + r) * 16 + kk * 4 + g];
            acc[0][ct] = __builtin_amdgcn_mfma_f32_16x16x32_bf16(a[0][kk], bfrag, acc[0][ct], 0, 0, 0);
            acc[1][ct] = __builtin_amdgcn_mfma_f32_16x16x32_bf16(a[1][kk], bfrag, acc[1][ct], 0, 0, 0);
        }
    }
    float qcv[4], wvv[4];
#pragma unroll
    for (int ct = 0; ct < 4; ++ct) {
        int c = 64 * wv + 16 * ct + r;
        qcv[ct] = qc[c];
        wvv[ct] = w[c];
    }
    const float HL2E = 0.72134752044448169f;   // 0.5*log2(e)
    float rs[2][4] = {};
#pragma unroll
    for (int s = 0; s < 2; ++s)
#pragma unroll
        for (int ct = 0; ct < 4; ++ct)
#pragma unroll
            for (int reg = 0; reg < 4; ++reg) {
                float e = (2.f * acc[s][ct][reg] - qxfin[16 * s + 4 * g + reg] - qcv[ct]) * HL2E;
                rs[s][reg] = fmaf(exp2f(e), wvv[ct], rs[s][reg]);
            }
#pragma unroll
    for (int s = 0; s < 2; ++s)
#pragma unroll
        for (int reg = 0; reg < 4; ++reg) {
            float v = rs[s][reg];
            v += __shfl_xor(v, 1); v += __shfl_xor(v, 2);
            v += __shfl_xor(v, 4); v += __shfl_xor(v, 8);
            if (r == 0) outlds[wv][16 * s + 4 * g + reg] = v;
        }
    __syncthreads();
    if (t < 32) {
        float s = 0.f;
#pragma unroll
        for (int i = 0; i < 8; ++i) s += outlds[i][t];
        out[n0 + t] = s;
    }
}

extern "C" void kernel_launch(void* const* d_in, const int* in_sizes, int n_in,
                              void* d_out, int out_size, void* d_ws, size_t ws_size,
                              hipStream_t stream) {
    const float* X       = (const float*)d_in[0];
    const float* pe      = (const float*)d_in[1];
    const float* centers = (const float*)d_in[2];
    const float* w       = (const float*)d_in[3];
    float* out = (float*)d_out;
    char* ws = (char*)d_ws;

    float* Pf  = (float*)(ws);                 // 128*128 f32      = 65536 B
    short* Pb  = (short*)(ws + 65536);         // 128*128 bf16     = 32768 B
    short* Xb  = (short*)(ws + 98304);         // 8192*128 bf16    = 2097152 B
    short* CPb = (short*)(ws + 2195456);       // 512*128 bf16     = 131072 B
    float* qc  = (float*)(ws + 2326528);       // 512 f32

    prep_kernel<<<576, 256, 0, stream>>>(pe, X, Pf, Pb, Xb);
    cpqc_kernel<<<64, 256, 0, stream>>>(centers, Pf, CPb, qc);
    mega_kernel<<<256, 512, 0, stream>>>(Xb, Pb, CPb, qc, w, out);
}

// Round 3
// 30.108 us; speedup vs baseline: 1.7300x; 1.2638x over previous
//
#include <hip/hip_runtime.h>

#define NS 8192
#define NC 512
#define NF 128

typedef short short8 __attribute__((ext_vector_type(8)));
typedef float f32x4 __attribute__((ext_vector_type(4)));

static __device__ __forceinline__ unsigned short f2bf(float f) {
    unsigned u = __float_as_uint(f);
    return (unsigned short)((u + 0x7fffu + ((u >> 16) & 1u)) >> 16);   // RNE
}

static __device__ __forceinline__ short8 pack8(const float* p) {
    float4 v0 = *(const float4*)p;
    float4 v1 = *(const float4*)(p + 4);
    short8 o;
    o[0] = (short)f2bf(v0.x); o[1] = (short)f2bf(v0.y);
    o[2] = (short)f2bf(v0.z); o[3] = (short)f2bf(v0.w);
    o[4] = (short)f2bf(v1.x); o[5] = (short)f2bf(v1.y);
    o[6] = (short)f2bf(v1.z); o[7] = (short)f2bf(v1.w);
    return o;
}

// L^T unpack into LDS, bf16, XOR-swizzled at 8-element (16 B) granule:
// element (row j = L-col, col i = L-row) stored at [j*128 + (i ^ ((j&7)<<3))]
__device__ __forceinline__ void unpack_LT(const float* __restrict__ pe, short* lt, int t, int nthr) {
    for (int idx = t; idx < NF * NF; idx += nthr) {
        int j = idx >> 7, i = idx & 127;           // LT[j][i] = L[i][j]
        float v = (j <= i) ? pe[i * (i + 1) / 2 + j] : 0.f;
        lt[j * NF + (i ^ ((j & 7) << 3))] = (short)f2bf(v);
    }
}

// ---------------- K1: blocks 0..31 -> V = centers@L (bf16) + q_c ; block 32 -> LT to global
__global__ __launch_bounds__(256) void k1_kernel(const float* __restrict__ pe,
                                                 const float* __restrict__ centers,
                                                 short* __restrict__ LTb,
                                                 short* __restrict__ Vb,
                                                 float* __restrict__ qc) {
    __shared__ short LT[NF * NF];
    __shared__ float qcw[4][16];
    int t = threadIdx.x, b = blockIdx.x;
    unpack_LT(pe, LT, t, 256);
    __syncthreads();

    if (b == 32) {       // write swizzled LT to global (linear copy, swizzle baked in)
        short8* dst = (short8*)LTb;
        const short8* src = (const short8*)LT;
#pragma unroll
        for (int i = 0; i < 8; ++i) dst[t + 256 * i] = src[t + 256 * i];
        return;
    }

    int wv = t >> 6, lane = t & 63, g = lane >> 4, r = lane & 15;
    int c0 = b * 16;
    // A fragments: center rows c0+r, k-chunk kk*32 + 8g
    short8 a[4];
#pragma unroll
    for (int kk = 0; kk < 4; ++kk)
        a[kk] = pack8(&centers[(size_t)(c0 + r) * NF + kk * 32 + 8 * g]);

    // wave wv covers f-cols [32*wv, 32*wv+32): 2 col-tiles
    f32x4 acc[2];
    acc[0] = (f32x4){0.f, 0.f, 0.f, 0.f};
    acc[1] = (f32x4){0.f, 0.f, 0.f, 0.f};
#pragma unroll
    for (int kk = 0; kk < 4; ++kk)
#pragma unroll
        for (int ct = 0; ct < 2; ++ct) {
            int row = 32 * wv + 16 * ct + r;   // LT row = f index
            short8 bf = *(const short8*)&LT[row * NF + ((kk * 32 + 8 * g) ^ ((row & 7) << 3))];
            acc[ct] = __builtin_amdgcn_mfma_f32_16x16x32_bf16(a[kk], bf, acc[ct], 0, 0, 0);
        }
    // V write (C/D layout: row = 4g+reg center-local, col = f-local = r) + q_c partials
#pragma unroll
    for (int reg = 0; reg < 4; ++reg) {
        float v = 0.f;
#pragma unroll
        for (int ct = 0; ct < 2; ++ct) {
            float x = acc[ct][reg];
            Vb[(size_t)(c0 + 4 * g + reg) * NF + 32 * wv + 16 * ct + r] = (short)f2bf(x);
            v = fmaf(x, x, v);
        }
        v += __shfl_xor(v, 1); v += __shfl_xor(v, 2);
        v += __shfl_xor(v, 4); v += __shfl_xor(v, 8);
        if (r == 0) qcw[wv][4 * g + reg] = v;
    }
    __syncthreads();
    if (t < 16) qc[c0 + t] = qcw[0][t] + qcw[1][t] + qcw[2][t] + qcw[3][t];
}

// ---------------- K2: U = X@L, q_x, cross = U V^T, exp epilogue -> out
__global__ __launch_bounds__(512) void k2_kernel(const float* __restrict__ X,
                                                 const short* __restrict__ LTb,
                                                 const short* __restrict__ Vb,
                                                 const float* __restrict__ qc,
                                                 const float* __restrict__ w,
                                                 float* __restrict__ out) {
    __shared__ short LT[NF * NF];        // 32 KB, swizzled
    __shared__ short Ulds[32 * NF];      // 8 KB, swizzled
    __shared__ float qxlds[8][32];
    __shared__ float qxfin[32];
    __shared__ float outlds[8][32];
    int t = threadIdx.x;
    int wv = t >> 6, lane = t & 63, g = lane >> 4, r = lane & 15;
    int n0 = blockIdx.x * 32;

    // stage LT (linear; swizzle pre-baked by K1)
    {
        short8* dst = (short8*)LT;
        const short8* src = (const short8*)LTb;
#pragma unroll
        for (int i = 0; i < 4; ++i) dst[t + 512 * i] = src[t + 512 * i];
    }
    // A fragments of X (fp32 -> bf16 in-register): rows n0+16s+r
    short8 a[2][4];
#pragma unroll
    for (int s = 0; s < 2; ++s)
#pragma unroll
        for (int kk = 0; kk < 4; ++kk)
            a[s][kk] = pack8(&X[(size_t)(n0 + 16 * s + r) * NF + kk * 32 + 8 * g]);
    __syncthreads();

    // ---------- phase 1: U = X@L, wave wv covers f-cols [16wv, 16wv+16)
    f32x4 aq[2];
    aq[0] = (f32x4){0.f, 0.f, 0.f, 0.f};
    aq[1] = (f32x4){0.f, 0.f, 0.f, 0.f};
#pragma unroll
    for (int kk = 0; kk < 4; ++kk) {
        int row = 16 * wv + r;
        short8 bf = *(const short8*)&LT[row * NF + ((kk * 32 + 8 * g) ^ ((row & 7) << 3))];
        aq[0] = __builtin_amdgcn_mfma_f32_16x16x32_bf16(a[0][kk], bf, aq[0], 0, 0, 0);
        aq[1] = __builtin_amdgcn_mfma_f32_16x16x32_bf16(a[1][kk], bf, aq[1], 0, 0, 0);
    }
    // q_x partials (sum of squares over this wave's 16 cols) + U -> LDS (bf16, swizzled)
#pragma unroll
    for (int s = 0; s < 2; ++s)
#pragma unroll
        for (int reg = 0; reg < 4; ++reg) {
            int rr = 16 * s + 4 * g + reg;
            float x = aq[s][reg];
            Ulds[rr * NF + ((16 * wv + r) ^ ((rr & 7) << 3))] = (short)f2bf(x);
            float v = x * x;
            v += __shfl_xor(v, 1); v += __shfl_xor(v, 2);
            v += __shfl_xor(v, 4); v += __shfl_xor(v, 8);
            if (r == 0) qxlds[wv][rr] = v;
        }
    __syncthreads();
    if (t < 32) {
        float s = 0.f;
#pragma unroll
        for (int i = 0; i < 8; ++i) s += qxlds[i][t];
        qxfin[t] = s;
    }
    // A fragments of U from LDS (swizzled read)
    short8 a2[2][4];
#pragma unroll
    for (int s = 0; s < 2; ++s)
#pragma unroll
        for (int kk = 0; kk < 4; ++kk) {
            int row = 16 * s + r;
            a2[s][kk] = *(const short8*)&Ulds[row * NF + ((kk * 32 + 8 * g) ^ ((row & 7) << 3))];
        }
    __syncthreads();

    // ---------- phase 2: cross vs centers [64*wv, 64*wv+64)
    f32x4 acc[2][4];
#pragma unroll
    for (int s = 0; s < 2; ++s)
#pragma unroll
        for (int ct = 0; ct < 4; ++ct) acc[s][ct] = (f32x4){0.f, 0.f, 0.f, 0.f};
    const short8* Vv = (const short8*)Vb;
#pragma unroll
    for (int kk = 0; kk < 4; ++kk)
#pragma unroll
        for (int ct = 0; ct < 4; ++ct) {
            short8 bf = Vv[(size_t)(64 * wv + 16 * ct + r) * 16 + kk * 4 + g];
            acc[0][ct] = __builtin_amdgcn_mfma_f32_16x16x32_bf16(a2[0][kk], bf, acc[0][ct], 0, 0, 0);
            acc[1][ct] = __builtin_amdgcn_mfma_f32_16x16x32_bf16(a2[1][kk], bf, acc[1][ct], 0, 0, 0);
        }
    float qcv[4], wvv[4];
#pragma unroll
    for (int ct = 0; ct < 4; ++ct) {
        int c = 64 * wv + 16 * ct + r;
        qcv[ct] = qc[c];
        wvv[ct] = w[c];
    }
    const float HL2E = 0.72134752044448169f;   // 0.5*log2(e)
    float rs[2][4] = {};
#pragma unroll
    for (int s = 0; s < 2; ++s)
#pragma unroll
        for (int ct = 0; ct < 4; ++ct)
#pragma unroll
            for (int reg = 0; reg < 4; ++reg) {
                float e = (2.f * acc[s][ct][reg] - qxfin[16 * s + 4 * g + reg] - qcv[ct]) * HL2E;
                rs[s][reg] = fmaf(exp2f(e), wvv[ct], rs[s][reg]);
            }
#pragma unroll
    for (int s = 0; s < 2; ++s)
#pragma unroll
        for (int reg = 0; reg < 4; ++reg) {
            float v = rs[s][reg];
            v += __shfl_xor(v, 1); v += __shfl_xor(v, 2);
            v += __shfl_xor(v, 4); v += __shfl_xor(v, 8);
            if (r == 0) outlds[wv][16 * s + 4 * g + reg] = v;
        }
    __syncthreads();
    if (t < 32) {
        float s = 0.f;
#pragma unroll
        for (int i = 0; i < 8; ++i) s += outlds[i][t];
        out[n0 + t] = s;
    }
}

extern "C" void kernel_launch(void* const* d_in, const int* in_sizes, int n_in,
                              void* d_out, int out_size, void* d_ws, size_t ws_size,
                              hipStream_t stream) {
    const float* X       = (const float*)d_in[0];
    const float* pe      = (const float*)d_in[1];
    const float* centers = (const float*)d_in[2];
    const float* w       = (const float*)d_in[3];
    float* out = (float*)d_out;
    char* ws = (char*)d_ws;

    short* LTb = (short*)(ws);              // 128*128 bf16 = 32768 B (swizzled)
    short* Vb  = (short*)(ws + 32768);      // 512*128 bf16 = 131072 B
    float* qc  = (float*)(ws + 163840);     // 512 f32

    k1_kernel<<<33, 256, 0, stream>>>(pe, centers, LTb, Vb, qc);
    k2_kernel<<<256, 512, 0, stream>>>(X, LTb, Vb, qc, w, out);
}